// Round 1
// baseline (147.684 us; speedup 1.0000x reference)
//
#include <hip/hip_runtime.h>
#include <cfloat>
#include <math.h>

namespace {
constexpr int   B              = 4;
constexpr int   N              = 8192;
constexpr int   KNN            = 16;
constexpr float EPSV           = 1e-12f;

constexpr int   THREADS        = 512;               // 8 waves
constexpr int   WAVES          = THREADS / 64;      // 8
constexpr int   ROWS_PER_WAVE  = 4;                 // each lane holds 4 query points
constexpr int   ROWS_PER_BLOCK = WAVES * ROWS_PER_WAVE;   // 32
constexpr int   BLOCKS_PER_BATCH = N / ROWS_PER_BLOCK;    // 256
constexpr int   GRID           = B * BLOCKS_PER_BATCH;    // 1024
constexpr int   TILE           = 2048;              // candidate points staged per LDS tile
constexpr int   NTILES         = N / TILE;          // 4
}

// ATOMIC=0: write per-block partial sums to outbuf[blockIdx.x] (reduced by kernel 2)
// ATOMIC=1: atomicAdd scaled partial into outbuf[0] (fallback if workspace too small)
template <int ATOMIC>
__global__ __launch_bounds__(THREADS, 1)
void knn_tv_kernel(const float* __restrict__ pc, float* __restrict__ outbuf)
{
    __shared__ float4 sPts[TILE];       // 32 KB
    __shared__ float  sWaveSum[WAVES];

    const int tid   = threadIdx.x;
    const int lane  = tid & 63;
    const int wave  = tid >> 6;
    const int blk   = blockIdx.x;
    const int batch = blk / BLOCKS_PER_BATCH;
    const int row0  = (blk % BLOCKS_PER_BATCH) * ROWS_PER_BLOCK;

    const float* base = pc + (size_t)batch * N * 3;

    // --- load this wave's 4 query points (same for all lanes of the wave) ---
    float qx[ROWS_PER_WAVE], qy[ROWS_PER_WAVE], qz[ROWS_PER_WAVE];
#pragma unroll
    for (int r = 0; r < ROWS_PER_WAVE; ++r) {
        const int row = row0 + wave * ROWS_PER_WAVE + r;
        qx[r] = base[row * 3 + 0];
        qy[r] = base[row * 3 + 1];
        qz[r] = base[row * 3 + 2];
    }

    // --- per-lane sorted (ascending) top-4 squared distances per row ---
    float lst[ROWS_PER_WAVE][4];
#pragma unroll
    for (int r = 0; r < ROWS_PER_WAVE; ++r)
#pragma unroll
        for (int i = 0; i < 4; ++i)
            lst[r][i] = FLT_MAX;

    for (int tile = 0; tile < NTILES; ++tile) {
        __syncthreads();   // protect sPts from previous iteration's readers
        // stage TILE candidate points as float4 into LDS (coalesced-ish 3x dword loads)
#pragma unroll
        for (int k = 0; k < TILE; k += THREADS) {
            const int p  = k + tid;
            const int gp = tile * TILE + p;
            sPts[p] = make_float4(base[gp * 3 + 0], base[gp * 3 + 1], base[gp * 3 + 2], 0.0f);
        }
        __syncthreads();

#pragma unroll 4
        for (int t = 0; t < TILE / 64; ++t) {
            const float4 c = sPts[t * 64 + lane];
#pragma unroll
            for (int r = 0; r < ROWS_PER_WAVE; ++r) {
                const float dx = c.x - qx[r];
                const float dy = c.y - qy[r];
                const float dz = c.z - qz[r];
                const float v  = fmaf(dz, dz, fmaf(dy, dy, dx * dx));
                // branchless sorted insertion (ascending), uses old values top-down
                lst[r][3] = fminf(lst[r][3], fmaxf(lst[r][2], v));
                lst[r][2] = fminf(lst[r][2], fmaxf(lst[r][1], v));
                lst[r][1] = fminf(lst[r][1], fmaxf(lst[r][0], v));
                lst[r][0] = fminf(lst[r][0], v);
            }
        }
    }

    // --- per-row wave merge: 16x (argmin over 64 lane-heads, pop winner) ---
    float wsum = 0.0f;
#pragma unroll
    for (int r = 0; r < ROWS_PER_WAVE; ++r) {
        float sum = 0.0f;
#pragma unroll
        for (int k = 0; k < KNN; ++k) {
            float m  = lst[r][0];
            int   ml = lane;
#pragma unroll
            for (int off = 1; off < 64; off <<= 1) {
                const float mv  = __shfl_xor(m, off, 64);
                const int   mll = __shfl_xor(ml, off, 64);
                if (mv < m || (mv == m && mll < ml)) { m = mv; ml = mll; }
            }
            sum += sqrtf(m + EPSV);
            if (lane == ml) {   // unique winner (lane-id tie-break) pops its head
                lst[r][0] = lst[r][1];
                lst[r][1] = lst[r][2];
                lst[r][2] = lst[r][3];
                lst[r][3] = FLT_MAX;
            }
        }
        wsum += sum;
    }

    if (lane == 0) sWaveSum[wave] = wsum;
    __syncthreads();
    if (tid == 0) {
        float t = 0.0f;
#pragma unroll
        for (int w = 0; w < WAVES; ++w) t += sWaveSum[w];
        if (ATOMIC) {
            atomicAdd(outbuf, t * (1.0f / (float)(B * N)));
        } else {
            outbuf[blk] = t;
        }
    }
}

__global__ __launch_bounds__(256, 1)
void knn_tv_reduce(const float* __restrict__ partial, float* __restrict__ out)
{
    __shared__ float s[4];
    const int tid = threadIdx.x;
    float v = 0.0f;
#pragma unroll
    for (int i = tid; i < GRID; i += 256) v += partial[i];
#pragma unroll
    for (int off = 1; off < 64; off <<= 1) v += __shfl_xor(v, off, 64);
    if ((tid & 63) == 0) s[tid >> 6] = v;
    __syncthreads();
    if (tid == 0) {
        const float t = s[0] + s[1] + s[2] + s[3];
        out[0] = t * (1.0f / (float)(B * N));
    }
}

extern "C" void kernel_launch(void* const* d_in, const int* in_sizes, int n_in,
                              void* d_out, int out_size, void* d_ws, size_t ws_size,
                              hipStream_t stream)
{
    const float* pc  = (const float*)d_in[0];
    float*       out = (float*)d_out;

    if (ws_size >= GRID * sizeof(float)) {
        float* partial = (float*)d_ws;
        knn_tv_kernel<0><<<GRID, THREADS, 0, stream>>>(pc, partial);
        knn_tv_reduce<<<1, 256, 0, stream>>>(partial, out);
    } else {
        // fallback: zero the scalar output, then atomically accumulate
        hipMemsetAsync(d_out, 0, sizeof(float), stream);
        knn_tv_kernel<1><<<GRID, THREADS, 0, stream>>>(pc, out);
    }
}

// Round 2
// 99.109 us; speedup vs baseline: 1.4901x; 1.4901x over previous
//
#include <hip/hip_runtime.h>
#include <cfloat>
#include <math.h>

namespace {
constexpr int   B              = 4;
constexpr int   N              = 8192;
constexpr int   KNN            = 16;
constexpr float EPSV           = 1e-12f;

constexpr int   THREADS        = 512;               // 8 waves
constexpr int   WAVES          = THREADS / 64;      // 8
constexpr int   ROWS_PER_WAVE  = 4;                 // each lane holds 4 query rows
constexpr int   ROWS_PER_BLOCK = WAVES * ROWS_PER_WAVE;   // 32
constexpr int   BLOCKS_PER_BATCH = N / ROWS_PER_BLOCK;    // 256
constexpr int   GRID           = B * BLOCKS_PER_BATCH;    // 1024
constexpr int   TILE           = 2048;              // candidate points staged per LDS tile
constexpr int   NTILES         = N / TILE;          // 4
constexpr int   TOPL           = 3;                 // per-lane top-L list
}

// ATOMIC=0: per-block partials to outbuf[blockIdx.x]; ATOMIC=1: atomicAdd into outbuf[0]
template <int ATOMIC>
__global__ __launch_bounds__(THREADS, 1)
void knn_tv_kernel(const float* __restrict__ pc, float* __restrict__ outbuf)
{
    __shared__ float4 sPts[TILE];       // 32 KB: (-2x, -2y, -2z, x^2+y^2+z^2)
    __shared__ float  sWaveSum[WAVES];

    const int tid   = threadIdx.x;
    const int lane  = tid & 63;
    const int wave  = tid >> 6;
    const int blk   = blockIdx.x;
    const int batch = blk / BLOCKS_PER_BATCH;
    const int row0  = (blk % BLOCKS_PER_BATCH) * ROWS_PER_BLOCK;

    const float* base = pc + (size_t)batch * N * 3;

    // --- this wave's 4 query points (uniform across lanes of the wave) ---
    float qx[ROWS_PER_WAVE], qy[ROWS_PER_WAVE], qz[ROWS_PER_WAVE], qs[ROWS_PER_WAVE];
#pragma unroll
    for (int r = 0; r < ROWS_PER_WAVE; ++r) {
        const int row = row0 + wave * ROWS_PER_WAVE + r;
        const float x = base[row * 3 + 0];
        const float y = base[row * 3 + 1];
        const float z = base[row * 3 + 2];
        qx[r] = x; qy[r] = y; qz[r] = z;
        qs[r] = fmaf(z, z, fmaf(y, y, x * x));
    }

    // --- per-lane sorted (ascending) top-3 squared distances per row ---
    float lst[ROWS_PER_WAVE][TOPL];
#pragma unroll
    for (int r = 0; r < ROWS_PER_WAVE; ++r)
#pragma unroll
        for (int i = 0; i < TOPL; ++i)
            lst[r][i] = FLT_MAX;

    for (int tile = 0; tile < NTILES; ++tile) {
        __syncthreads();   // protect sPts from previous iteration's readers
        // stage TILE candidates, pre-transformed for gram-form distance
#pragma unroll
        for (int k = 0; k < TILE; k += THREADS) {
            const int p  = k + tid;
            const int gp = tile * TILE + p;
            const float x = base[gp * 3 + 0];
            const float y = base[gp * 3 + 1];
            const float z = base[gp * 3 + 2];
            const float s = fmaf(z, z, fmaf(y, y, x * x));
            sPts[p] = make_float4(-2.0f * x, -2.0f * y, -2.0f * z, s);
        }
        __syncthreads();

#pragma unroll 4
        for (int t = 0; t < TILE / 64; ++t) {
            const float4 c = sPts[t * 64 + lane];
#pragma unroll
            for (int r = 0; r < ROWS_PER_WAVE; ++r) {
                // d^2 = csq + qsq - 2*(c.q): 1 add + 3 fma
                const float v = fmaf(c.x, qx[r],
                                fmaf(c.y, qy[r],
                                fmaf(c.z, qz[r], c.w + qs[r])));
                // branchless sorted insertion into ascending top-3 (5 ops)
                lst[r][2] = fminf(lst[r][2], fmaxf(lst[r][1], v));
                lst[r][1] = fminf(lst[r][1], fmaxf(lst[r][0], v));
                lst[r][0] = fminf(lst[r][0], v);
            }
        }
    }

    // --- per-row wave merge: 16x (min over 64 lane-heads, pop winner) ---
    // k-outer / r-inner so the 4 rows' shuffle chains interleave.
    float rsum[ROWS_PER_WAVE];
#pragma unroll
    for (int r = 0; r < ROWS_PER_WAVE; ++r) rsum[r] = 0.0f;

#pragma unroll
    for (int k = 0; k < KNN; ++k) {
#pragma unroll
        for (int r = 0; r < ROWS_PER_WAVE; ++r) {
            float m = lst[r][0];
#pragma unroll
            for (int off = 1; off < 64; off <<= 1)
                m = fminf(m, __shfl_xor(m, off, 64));
            const unsigned long long bal = __ballot(lst[r][0] == m);
            const int first = __builtin_ctzll(bal);
            rsum[r] += sqrtf(fmaxf(m, 0.0f) + EPSV);
            if (lane == first) {   // lowest lane among ties pops its head
                lst[r][0] = lst[r][1];
                lst[r][1] = lst[r][2];
                lst[r][2] = FLT_MAX;
            }
        }
    }

    float wsum = 0.0f;
#pragma unroll
    for (int r = 0; r < ROWS_PER_WAVE; ++r) wsum += rsum[r];

    if (lane == 0) sWaveSum[wave] = wsum;
    __syncthreads();
    if (tid == 0) {
        float t = 0.0f;
#pragma unroll
        for (int w = 0; w < WAVES; ++w) t += sWaveSum[w];
        if (ATOMIC) {
            atomicAdd(outbuf, t * (1.0f / (float)(B * N)));
        } else {
            outbuf[blk] = t;
        }
    }
}

__global__ __launch_bounds__(256, 1)
void knn_tv_reduce(const float* __restrict__ partial, float* __restrict__ out)
{
    __shared__ float s[4];
    const int tid = threadIdx.x;
    float v = 0.0f;
#pragma unroll
    for (int i = tid; i < GRID; i += 256) v += partial[i];
#pragma unroll
    for (int off = 1; off < 64; off <<= 1) v += __shfl_xor(v, off, 64);
    if ((tid & 63) == 0) s[tid >> 6] = v;
    __syncthreads();
    if (tid == 0) {
        const float t = s[0] + s[1] + s[2] + s[3];
        out[0] = t * (1.0f / (float)(B * N));
    }
}

extern "C" void kernel_launch(void* const* d_in, const int* in_sizes, int n_in,
                              void* d_out, int out_size, void* d_ws, size_t ws_size,
                              hipStream_t stream)
{
    const float* pc  = (const float*)d_in[0];
    float*       out = (float*)d_out;

    if (ws_size >= GRID * sizeof(float)) {
        float* partial = (float*)d_ws;
        knn_tv_kernel<0><<<GRID, THREADS, 0, stream>>>(pc, partial);
        knn_tv_reduce<<<1, 256, 0, stream>>>(partial, out);
    } else {
        hipMemsetAsync(d_out, 0, sizeof(float), stream);
        knn_tv_kernel<1><<<GRID, THREADS, 0, stream>>>(pc, out);
    }
}

// Round 3
// 80.225 us; speedup vs baseline: 1.8409x; 1.2354x over previous
//
#include <hip/hip_runtime.h>
#include <cfloat>
#include <math.h>

namespace {
constexpr int   B      = 4;
constexpr int   N      = 8192;
constexpr int   KNN    = 16;
constexpr float EPSV   = 1e-12f;

constexpr int   THREADS = 512;            // 8 waves
constexpr int   WAVES   = THREADS / 64;   // 8
constexpr int   RPW     = 4;              // query rows per wave
constexpr int   RPB     = WAVES * RPW;    // 32 rows per block
constexpr int   BPB     = N / RPB;        // 256 blocks per batch
constexpr int   GRID    = B * BPB;        // 1024
constexpr int   TILE    = 512;            // candidates per LDS tile (== THREADS)
constexpr int   NTILES  = N / TILE;       // 16
}

__device__ __forceinline__ float rfl(float x) {
    // wave-uniform value -> SGPR
    return __int_as_float(__builtin_amdgcn_readfirstlane(__float_as_int(x)));
}

// ATOMIC=0: per-block partials to outbuf[blockIdx.x]; ATOMIC=1: atomicAdd into outbuf[0]
template <int ATOMIC>
__global__ __launch_bounds__(THREADS, 1)
void knn_tv_kernel(const float* __restrict__ pc, float* __restrict__ outbuf)
{
    __shared__ float sX[TILE], sY[TILE], sZ[TILE], sS[TILE];   // 8 KB SoA
    __shared__ float sWaveSum[WAVES];

    const int tid   = threadIdx.x;
    const int lane  = tid & 63;
    const int wave  = tid >> 6;
    const int blk   = blockIdx.x;
    const int batch = blk / BPB;
    const int row0  = (blk % BPB) * RPB + wave * RPW;

    const float* __restrict__ base = pc + (size_t)batch * (size_t)N * 3;

    // Query scalars (wave-uniform -> SGPR). Fold -2 into q; qs re-added at pop time.
    float qx[RPW], qy[RPW], qz[RPW], qs[RPW];
#pragma unroll
    for (int r = 0; r < RPW; ++r) {
        const int row = row0 + r;
        const float x = base[row * 3 + 0];
        const float y = base[row * 3 + 1];
        const float z = base[row * 3 + 2];
        qx[r] = rfl(-2.0f * x);
        qy[r] = rfl(-2.0f * y);
        qz[r] = rfl(-2.0f * z);
        qs[r] = rfl(fmaf(z, z, fmaf(y, y, x * x)));
    }

    // Per-(lane, slot) stream minima of v = |c|^2 - 2 q.c  (8 slots per lane)
    float m0[RPW][8];
#pragma unroll
    for (int r = 0; r < RPW; ++r)
#pragma unroll
        for (int c = 0; c < 8; ++c)
            m0[r][c] = FLT_MAX;

    for (int tile = 0; tile < NTILES; ++tile) {
        __syncthreads();   // protect SoA from previous tile's readers
        {
            const int p  = tid;              // TILE == THREADS
            const int gp = tile * TILE + p;
            const float x = base[gp * 3 + 0];
            const float y = base[gp * 3 + 1];
            const float z = base[gp * 3 + 2];
            sX[p] = x; sY[p] = y; sZ[p] = z;
            sS[p] = fmaf(z, z, fmaf(y, y, x * x));
        }
        __syncthreads();

        const int i0 = 4 * lane;         // contiguous b128 pattern, conflict-free
        const int i1 = 256 + 4 * lane;
        const float4 X0 = *(const float4*)&sX[i0], X1 = *(const float4*)&sX[i1];
        const float4 Y0 = *(const float4*)&sY[i0], Y1 = *(const float4*)&sY[i1];
        const float4 Z0 = *(const float4*)&sZ[i0], Z1 = *(const float4*)&sZ[i1];
        const float4 S0 = *(const float4*)&sS[i0], S1 = *(const float4*)&sS[i1];
        const float cx[8] = {X0.x, X0.y, X0.z, X0.w, X1.x, X1.y, X1.z, X1.w};
        const float cy[8] = {Y0.x, Y0.y, Y0.z, Y0.w, Y1.x, Y1.y, Y1.z, Y1.w};
        const float cz[8] = {Z0.x, Z0.y, Z0.z, Z0.w, Z1.x, Z1.y, Z1.z, Z1.w};
        const float cs[8] = {S0.x, S0.y, S0.z, S0.w, S1.x, S1.y, S1.z, S1.w};

#pragma unroll
        for (int r = 0; r < RPW; ++r) {
#pragma unroll
            for (int c = 0; c < 8; ++c) {
                const float v = fmaf(cx[c], qx[r],
                                fmaf(cy[c], qy[r],
                                fmaf(cz[c], qz[r], cs[c])));
                m0[r][c] = fminf(m0[r][c], v);   // 3 fma + 1 min per pair
            }
        }
    }

    // --- per lane: sorted top-4 of its 8 stream minima (per row) ---
    float L[RPW][4];
    float racc[RPW];
#pragma unroll
    for (int r = 0; r < RPW; ++r) {
        const float a0 = fminf(m0[r][0], m0[r][1]), b0 = fmaxf(m0[r][0], m0[r][1]);
        const float a1 = fminf(m0[r][2], m0[r][3]), b1 = fmaxf(m0[r][2], m0[r][3]);
        const float a2 = fminf(m0[r][4], m0[r][5]), b2 = fmaxf(m0[r][4], m0[r][5]);
        const float a3 = fminf(m0[r][6], m0[r][7]), b3 = fmaxf(m0[r][6], m0[r][7]);
        // sorted-4 P from (a0,b0),(a1,b1); sorted-4 Q from (a2,b2),(a3,b3)
        const float p0 = fminf(a0, a1), xP = fmaxf(a0, a1), yP = fminf(b0, b1), p3 = fmaxf(b0, b1);
        const float p1 = fminf(xP, yP), p2 = fmaxf(xP, yP);
        const float q0 = fminf(a2, a3), xQ = fmaxf(a2, a3), yQ = fminf(b2, b3), q3 = fmaxf(b2, b3);
        const float q1 = fminf(xQ, yQ), q2 = fmaxf(xQ, yQ);
        // bitonic low-4 of P x reverse(Q), then sort the bitonic 4-seq
        const float l0 = fminf(p0, q3), l1 = fminf(p1, q2), l2 = fminf(p2, q1), l3 = fminf(p3, q0);
        const float t0 = fminf(l0, l2), t2 = fmaxf(l0, l2);
        const float t1 = fminf(l1, l3), t3 = fmaxf(l1, l3);
        L[r][0] = fminf(t0, t1); L[r][1] = fmaxf(t0, t1);
        L[r][2] = fminf(t2, t3); L[r][3] = fmaxf(t2, t3);
        racc[r] = 0.0f;
    }

    // --- 16 pops per row; k-outer/r-inner so 4 shuffle chains interleave ---
#pragma unroll
    for (int k = 0; k < KNN; ++k) {
#pragma unroll
        for (int r = 0; r < RPW; ++r) {
            float m = L[r][0];
            m = fminf(m, __shfl_xor(m, 1, 64));
            m = fminf(m, __shfl_xor(m, 2, 64));
            m = fminf(m, __shfl_xor(m, 4, 64));
            m = fminf(m, __shfl_xor(m, 8, 64));
            m = fminf(m, __shfl_xor(m, 16, 64));
            m = fminf(m, __shfl_xor(m, 32, 64));
            racc[r] += sqrtf(fmaxf(qs[r] + m, 0.0f) + EPSV);
            const bool take = (L[r][0] == m);   // exact ties multi-pop: sum unchanged
            L[r][0] = take ? L[r][1] : L[r][0];
            L[r][1] = take ? L[r][2] : L[r][1];
            L[r][2] = take ? L[r][3] : L[r][2];
            L[r][3] = take ? FLT_MAX : L[r][3];
        }
    }

    float wsum = 0.0f;
#pragma unroll
    for (int r = 0; r < RPW; ++r) wsum += racc[r];

    if (lane == 0) sWaveSum[wave] = wsum;
    __syncthreads();
    if (tid == 0) {
        float t = 0.0f;
#pragma unroll
        for (int w = 0; w < WAVES; ++w) t += sWaveSum[w];
        if (ATOMIC) {
            atomicAdd(outbuf, t * (1.0f / (float)(B * N)));
        } else {
            outbuf[blk] = t;
        }
    }
}

__global__ __launch_bounds__(256, 1)
void knn_tv_reduce(const float* __restrict__ partial, float* __restrict__ out)
{
    __shared__ float s[4];
    const int tid = threadIdx.x;
    float v = 0.0f;
#pragma unroll
    for (int i = tid; i < GRID; i += 256) v += partial[i];
#pragma unroll
    for (int off = 1; off < 64; off <<= 1) v += __shfl_xor(v, off, 64);
    if ((tid & 63) == 0) s[tid >> 6] = v;
    __syncthreads();
    if (tid == 0) {
        const float t = s[0] + s[1] + s[2] + s[3];
        out[0] = t * (1.0f / (float)(B * N));
    }
}

extern "C" void kernel_launch(void* const* d_in, const int* in_sizes, int n_in,
                              void* d_out, int out_size, void* d_ws, size_t ws_size,
                              hipStream_t stream)
{
    const float* pc  = (const float*)d_in[0];
    float*       out = (float*)d_out;

    if (ws_size >= GRID * sizeof(float)) {
        float* partial = (float*)d_ws;
        knn_tv_kernel<0><<<GRID, THREADS, 0, stream>>>(pc, partial);
        knn_tv_reduce<<<1, 256, 0, stream>>>(partial, out);
    } else {
        hipMemsetAsync(d_out, 0, sizeof(float), stream);
        knn_tv_kernel<1><<<GRID, THREADS, 0, stream>>>(pc, out);
    }
}